// Round 15
// baseline (866.570 us; speedup 1.0000x reference)
//
#include <hip/hip_runtime.h>
#include <cstdint>
#include <cstddef>

typedef __attribute__((ext_vector_type(8))) short bf16x8;
typedef __attribute__((ext_vector_type(8))) unsigned short u16x8;
typedef __attribute__((ext_vector_type(4))) float f32x4;

static inline int ceil_div(int a, int b){ return (a + b - 1) / b; }

struct HL { short h, l; };
__device__ inline HL split2(float a){
  unsigned u = __float_as_uint(a);
  unsigned hb = (u + 0x8000u) & 0xFFFF0000u;
  float r = a - __uint_as_float(hb);
  HL o;
  o.h = (short)(hb >> 16);
  o.l = (short)((__float_as_uint(r) + 0x8000u) >> 16);
  return o;
}

__device__ inline unsigned short f2b(float f){            // fp32 -> bf16 (RNE)
  unsigned u = __float_as_uint(f);
  unsigned r = u + 0x7FFFu + ((u >> 16) & 1u);
  return (unsigned short)(r >> 16);
}
__device__ inline float b2f(unsigned short s){
  return __uint_as_float((unsigned)s << 16);
}
__device__ inline float b2f_lo(unsigned v){ return __uint_as_float(v << 16); }
__device__ inline float b2f_hi(unsigned v){ return __uint_as_float(v & 0xFFFF0000u); }

#define EPB 4096   // edges per histogram/partition block

// ---------------- dtype detection (int64 vs int32 edge_index) ----------------
__global__ __launch_bounds__(256) void k_detect(const int* __restrict__ ei32, int E, int* __restrict__ flag){
  int t = blockIdx.x * 256 + threadIdx.x;
  if (t < 4096) {
    long long idx = 2LL * t + 1;
    if (idx < 2LL * E && ei32[idx] != 0) atomicOr(flag, 1);
  }
}

// ---------------- CSR build v2: counting sort by dst bucket (dst>>8) ----------------
__global__ __launch_bounds__(256) void k_hist(const void* __restrict__ ei, int E,
                                              const int* __restrict__ flag, int* __restrict__ block_hist){
  __shared__ int h[512];
  for (int i = threadIdx.x; i < 512; i += 256) h[i] = 0;
  __syncthreads();
  int base = blockIdx.x * EPB;
  bool is32 = (*flag != 0);
  for (int i = 0; i < 16; ++i){
    int e = base + i * 256 + threadIdx.x;
    if (e < E){
      int dst = is32 ? ((const int*)ei)[(size_t)E + e] : (int)((const long long*)ei)[(size_t)E + e];
      atomicAdd(&h[dst >> 8], 1);
    }
  }
  __syncthreads();
  for (int i = threadIdx.x; i < 512; i += 256) block_hist[blockIdx.x * 512 + i] = h[i];
}

__global__ __launch_bounds__(64) void k_colscan(const int* __restrict__ block_hist, int* __restrict__ off_hist,
                                                int* __restrict__ bucket_total, int nblk){
  int k = blockIdx.x;
  int lane = threadIdx.x;
  int carry = 0;
  for (int c = 0; c * 64 < nblk; ++c){
    int b = c * 64 + lane;
    int v = (b < nblk) ? block_hist[b * 512 + k] : 0;
    int inc = v;
#pragma unroll
    for (int off = 1; off < 64; off <<= 1){
      int u = __shfl_up(inc, off);
      if (lane >= off) inc += u;
    }
    if (b < nblk) off_hist[b * 512 + k] = carry + inc - v;
    carry += __shfl(inc, 63);
  }
  if (lane == 0) bucket_total[k] = carry;
}

__global__ __launch_bounds__(512) void k_bucketbase(const int* __restrict__ bucket_total,
                                                    int* __restrict__ bucket_base,
                                                    int* __restrict__ row_ptr, int N, int E){
  __shared__ int sh[512];
  int t = threadIdx.x;
  int v = bucket_total[t];
  sh[t] = v; __syncthreads();
  for (int off = 1; off < 512; off <<= 1){
    int u = (t >= off) ? sh[t - off] : 0;
    __syncthreads();
    sh[t] += u;
    __syncthreads();
  }
  bucket_base[t] = sh[t] - v;
  if (t == 511) bucket_base[512] = sh[511];
  if (t == 0) row_ptr[N] = E;
}

__global__ __launch_bounds__(256) void k_partition(const void* __restrict__ ei, const float* __restrict__ ew,
                                                   int E, const int* __restrict__ flag,
                                                   const int* __restrict__ off_hist,
                                                   const int* __restrict__ bucket_base,
                                                   uint2* __restrict__ part){
  __shared__ int cur[512];
  for (int i = threadIdx.x; i < 512; i += 256)
    cur[i] = off_hist[blockIdx.x * 512 + i] + bucket_base[i];
  __syncthreads();
  int base = blockIdx.x * EPB;
  bool is32 = (*flag != 0);
  for (int i = 0; i < 16; ++i){
    int e = base + i * 256 + threadIdx.x;
    if (e < E){
      int src, dst;
      if (is32){ src = ((const int*)ei)[e]; dst = ((const int*)ei)[(size_t)E + e]; }
      else     { src = (int)((const long long*)ei)[e]; dst = (int)((const long long*)ei)[(size_t)E + e]; }
      int pos = atomicAdd(&cur[dst >> 8], 1);
      part[pos] = make_uint2((unsigned)src | ((unsigned)(dst & 255) << 20), __float_as_uint(ew[e]));
    }
  }
}

__global__ __launch_bounds__(256) void k_bucket_csr(const uint2* __restrict__ part,
                                                    const int* __restrict__ bucket_base,
                                                    uint2* __restrict__ csr_sw, int* __restrict__ row_ptr,
                                                    float* __restrict__ dis1, float* __restrict__ dis2,
                                                    float* __restrict__ invw, int N){
  __shared__ int cnt[256];
  __shared__ float wsum[256];
  __shared__ int cursor[256];
  __shared__ int ws[4];
  int k = blockIdx.x;
  int t = threadIdx.x;
  int base = bucket_base[k], end = bucket_base[k + 1];
  cnt[t] = 0; wsum[t] = 0.f;
  __syncthreads();
  for (int i = base + t; i < end; i += 256){
    uint2 rec = part[i];
    int dstl = (rec.x >> 20) & 255;
    atomicAdd(&cnt[dstl], 1);
    atomicAdd(&wsum[dstl], __uint_as_float(rec.y));
  }
  __syncthreads();
  int v = cnt[t];
  int lane = t & 63;
  int inc = v;
#pragma unroll
  for (int off = 1; off < 64; off <<= 1){
    int u = __shfl_up(inc, off);
    if (lane >= off) inc += u;
  }
  if (lane == 63) ws[t >> 6] = inc;
  __syncthreads();
  int woff = 0;
  for (int i = 0; i < (t >> 6); ++i) woff += ws[i];
  int exc = woff + inc - v;
  int node = k * 256 + t;
  if (node < N){
    row_ptr[node] = base + exc;
    float s = wsum[t];
    dis1[node] = rsqrtf(s + 1.0f);
    dis2[node] = (s > 0.f) ? rsqrtf(s) : 0.f;
    invw[node] = 1.0f / (float)(v + 1);
  }
  cursor[t] = exc;
  __syncthreads();
  for (int i = base + t; i < end; i += 256){
    uint2 rec = part[i];
    int dstl = (rec.x >> 20) & 255;
    int pos = base + atomicAdd(&cursor[dstl], 1);
    csr_sw[pos] = make_uint2(rec.x & 0xFFFFFu, rec.y);
  }
}

// ---------------- edge norms: packed (src, w) streams for gcn and cheb ----------------
__global__ __launch_bounds__(256) void k_norm(const uint2* __restrict__ csr_sw,
                                              const float* __restrict__ dis1, const float* __restrict__ dis2,
                                              uint2* __restrict__ pk_gcn, uint2* __restrict__ pk_cheb, int E){
  int e = blockIdx.x * 256 + threadIdx.x;
  if (e >= E) return;
  uint2 p = csr_sw[e];
  int s = (int)p.x;
  float w = __uint_as_float(p.y);
  pk_gcn[e]  = make_uint2(p.x, __float_as_uint(w * dis1[s]));
  pk_cheb[e] = make_uint2(p.x, __float_as_uint(w * dis2[s]));
}

// ---------------- weight prep ----------------
__global__ __launch_bounds__(256) void k_prep_w(const float* __restrict__ W, short* __restrict__ Wh,
                                                short* __restrict__ Wl, int K, int N){
  int idx = blockIdx.x * 256 + threadIdx.x;
  if (idx >= K * N) return;
  int n = idx / K, k = idx - n * K;
  HL s = split2(W[(size_t)k * N + n]);
  Wh[idx] = s.h; Wl[idx] = s.l;
}

__global__ __launch_bounds__(256) void k_prep_wc(const float* __restrict__ Wc, short* __restrict__ Wh){
  int idx = blockIdx.x * 256 + threadIdx.x;
  if (idx >= 768 * 256) return;
  int n = idx >> 8, k = idx & 255;
  Wh[idx] = (short)f2b(Wc[(size_t)(n >> 7) * 256 * 128 + (size_t)k * 128 + (n & 127)]);
}

// ---------------- MFMA GEMM 1: A = bf16(x), B = W1 split; 2-term; A reg-prefetch; XCD swizzle ----
__global__ __launch_bounds__(256) void k_gemm_mfma(
    const float* __restrict__ A,
    const short* __restrict__ Bh, const short* __restrict__ Bl,
    unsigned short* __restrict__ Cb,
    int M, int Ncols, int K, int nbm)
{
  __shared__ short Ah[128][40];
  __shared__ short Bhs[128][40];
  __shared__ short Bls[128][40];
  int bid = blockIdx.x;
  int g = bid & 7, j = bid >> 3;
  int m_tile = g + 8 * (j >> 1);
  int n_tile = j & 1;
  if (m_tile >= nbm) return;
  int m0 = m_tile * 128, n0 = n_tile * 128;
  int t = threadIdx.x;
  int lane = t & 63, wid = t >> 6;
  int wr = wid >> 1, wc = wid & 1;
  int fr = lane & 15, fq = lane >> 4;
  int srow = t >> 1, skh = (t & 1) << 4;

  f32x4 acc[4][4];
#pragma unroll
  for (int i = 0; i < 4; ++i)
#pragma unroll
    for (int jj = 0; jj < 4; ++jj) acc[i][jj] = (f32x4){0.f, 0.f, 0.f, 0.f};

  bool aval = (m0 + srow) < M;
  const float* Aptr = A + (size_t)(m0 + srow) * K + skh;
  const short* Bhp = Bh + (size_t)(n0 + srow) * K + skh;
  const short* Blp = Bl + (size_t)(n0 + srow) * K + skh;

  float4 a0, a1, a2, a3;
  if (aval){
    const float4* ap = (const float4*)Aptr;
    a0 = ap[0]; a1 = ap[1]; a2 = ap[2]; a3 = ap[3];
  } else a0 = a1 = a2 = a3 = make_float4(0.f, 0.f, 0.f, 0.f);

  for (int k0 = 0; k0 < K; k0 += 32){
    bf16x8 h0, h1;
    h0[0]=(short)f2b(a0.x); h0[1]=(short)f2b(a0.y); h0[2]=(short)f2b(a0.z); h0[3]=(short)f2b(a0.w);
    h0[4]=(short)f2b(a1.x); h0[5]=(short)f2b(a1.y); h0[6]=(short)f2b(a1.z); h0[7]=(short)f2b(a1.w);
    h1[0]=(short)f2b(a2.x); h1[1]=(short)f2b(a2.y); h1[2]=(short)f2b(a2.z); h1[3]=(short)f2b(a2.w);
    h1[4]=(short)f2b(a3.x); h1[5]=(short)f2b(a3.y); h1[6]=(short)f2b(a3.z); h1[7]=(short)f2b(a3.w);
    *(bf16x8*)&Ah[srow][skh]     = h0;
    *(bf16x8*)&Ah[srow][skh + 8] = h1;
    {
      const bf16x8* bp = (const bf16x8*)(Bhp + k0);
      *(bf16x8*)&Bhs[srow][skh]     = bp[0];
      *(bf16x8*)&Bhs[srow][skh + 8] = bp[1];
      const bf16x8* cp = (const bf16x8*)(Blp + k0);
      *(bf16x8*)&Bls[srow][skh]     = cp[0];
      *(bf16x8*)&Bls[srow][skh + 8] = cp[1];
    }
    __syncthreads();
    bool more = (k0 + 32) < K;
    float4 n0v, n1v, n2v, n3v;
    if (more && aval){
      const float4* ap = (const float4*)(Aptr + k0 + 32);
      n0v = ap[0]; n1v = ap[1]; n2v = ap[2]; n3v = ap[3];
    } else n0v = n1v = n2v = n3v = make_float4(0.f, 0.f, 0.f, 0.f);
    bf16x8 afh[4], bfh[4], bfl[4];
#pragma unroll
    for (int m = 0; m < 4; ++m){
      int r = wr * 64 + m * 16 + fr;
      afh[m] = *(const bf16x8*)&Ah[r][fq * 8];
    }
#pragma unroll
    for (int n = 0; n < 4; ++n){
      int r = wc * 64 + n * 16 + fr;
      bfh[n] = *(const bf16x8*)&Bhs[r][fq * 8];
      bfl[n] = *(const bf16x8*)&Bls[r][fq * 8];
    }
#pragma unroll
    for (int m = 0; m < 4; ++m)
#pragma unroll
      for (int n = 0; n < 4; ++n){
        acc[m][n] = __builtin_amdgcn_mfma_f32_16x16x32_bf16(afh[m], bfh[n], acc[m][n], 0, 0, 0);
        acc[m][n] = __builtin_amdgcn_mfma_f32_16x16x32_bf16(afh[m], bfl[n], acc[m][n], 0, 0, 0);
      }
    __syncthreads();
    a0 = n0v; a1 = n1v; a2 = n2v; a3 = n3v;
  }
#pragma unroll
  for (int m = 0; m < 4; ++m){
#pragma unroll
    for (int n = 0; n < 4; ++n){
      int col = n0 + wc * 64 + n * 16 + fr;
#pragma unroll
      for (int r = 0; r < 4; ++r){
        int row = m0 + wr * 64 + m * 16 + fq * 4 + r;
        if (row < M){
          Cb[(size_t)row * Ncols + col] = f2b(acc[m][n][r]);
        }
      }
    }
  }
}

// ---------------- MFMA GEMM 2: A = bf16(h1), B = bf16(Wc); single term; reg-prefetch; XCD swizzle ----
__global__ __launch_bounds__(256) void k_gemm_mfma2(
    const unsigned short* __restrict__ Ahg,
    const short* __restrict__ Bh,
    unsigned short* __restrict__ Cb, unsigned short* __restrict__ C5c,
    int M, int Ncols, int K, int nbm)
{
  __shared__ short Ah[128][40];
  __shared__ short Bhs[128][40];
  int bid = blockIdx.x;
  int g = bid & 7, j = bid >> 3;
  int m_tile = g + 8 * (j / 6);
  int n_tile = j - 6 * (j / 6);
  if (m_tile >= nbm) return;
  int m0 = m_tile * 128, n0 = n_tile * 128;
  int t = threadIdx.x;
  int lane = t & 63, wid = t >> 6;
  int wr = wid >> 1, wc = wid & 1;
  int fr = lane & 15, fq = lane >> 4;
  int srow = t >> 1, skh = (t & 1) << 4;

  f32x4 acc[4][4];
#pragma unroll
  for (int i = 0; i < 4; ++i)
#pragma unroll
    for (int jj = 0; jj < 4; ++jj) acc[i][jj] = (f32x4){0.f, 0.f, 0.f, 0.f};

  bool aval = (m0 + srow) < M;
  const unsigned short* Ahp = Ahg + (size_t)(m0 + srow) * K + skh;
  const short* Bhp = Bh + (size_t)(n0 + srow) * K + skh;

  bf16x8 ch0, ch1;
  if (aval){
    const bf16x8* ah = (const bf16x8*)Ahp;
    ch0 = ah[0]; ch1 = ah[1];
  } else {
    bf16x8 z = (bf16x8){0,0,0,0,0,0,0,0};
    ch0 = ch1 = z;
  }

  for (int k0 = 0; k0 < K; k0 += 32){
    *(bf16x8*)&Ah[srow][skh]     = ch0;
    *(bf16x8*)&Ah[srow][skh + 8] = ch1;
    {
      const bf16x8* bp = (const bf16x8*)(Bhp + k0);
      *(bf16x8*)&Bhs[srow][skh]     = bp[0];
      *(bf16x8*)&Bhs[srow][skh + 8] = bp[1];
    }
    __syncthreads();
    bool more = (k0 + 32) < K;
    bf16x8 nh0, nh1;
    if (more && aval){
      const bf16x8* ah = (const bf16x8*)(Ahp + k0 + 32);
      nh0 = ah[0]; nh1 = ah[1];
    } else {
      bf16x8 z = (bf16x8){0,0,0,0,0,0,0,0};
      nh0 = nh1 = z;
    }
    bf16x8 afh[4], bfh[4];
#pragma unroll
    for (int m = 0; m < 4; ++m){
      int r = wr * 64 + m * 16 + fr;
      afh[m] = *(const bf16x8*)&Ah[r][fq * 8];
    }
#pragma unroll
    for (int n = 0; n < 4; ++n){
      int r = wc * 64 + n * 16 + fr;
      bfh[n] = *(const bf16x8*)&Bhs[r][fq * 8];
    }
#pragma unroll
    for (int m = 0; m < 4; ++m)
#pragma unroll
      for (int n = 0; n < 4; ++n){
        acc[m][n] = __builtin_amdgcn_mfma_f32_16x16x32_bf16(afh[m], bfh[n], acc[m][n], 0, 0, 0);
      }
    __syncthreads();
    ch0 = nh0; ch1 = nh1;
  }
#pragma unroll
  for (int m = 0; m < 4; ++m){
#pragma unroll
    for (int n = 0; n < 4; ++n){
      int col = n0 + wc * 64 + n * 16 + fr;
#pragma unroll
      for (int r = 0; r < 4; ++r){
        int row = m0 + wr * 64 + m * 16 + fq * 4 + r;
        if (row < M){
          unsigned short v = f2b(acc[m][n][r]);
          Cb[(size_t)row * Ncols + col] = v;
          if (n_tile == 5) C5c[(size_t)row * 128 + (col - 640)] = v;
        }
      }
    }
  }
}

// ---------------- GCN aggregation: half-wave, 16-edge unroll (8 gathers in flight/half) ----------
__global__ __launch_bounds__(256) void k_gcn_agg(
    const unsigned short* __restrict__ h0b,
    const uint2* __restrict__ pk, const int* __restrict__ row_ptr,
    const float* __restrict__ dis1, const float* __restrict__ b1,
    unsigned short* __restrict__ h1b, int N){
  int lane = threadIdx.x & 63;
  int r = blockIdx.x * 4 + (threadIdx.x >> 6);
  if (r >= N) return;
  int half = lane >> 5;
  int sub  = lane & 31;              // cols sub*8 .. sub*8+7
  float dr = dis1[r];
  u16x8 sv = ((const u16x8*)(h0b + (size_t)r * 256))[sub];
  float hsc = (half == 0) ? dr : 0.f;
  float acc[8];
#pragma unroll
  for (int j = 0; j < 8; ++j) acc[j] = hsc * b2f(sv[j]);
  int e0 = row_ptr[r], e1 = row_ptr[r + 1];
  int e = e0;
  for (; e + 16 <= e1; e += 16){
    uint2 pv[8]; u16x8 vi[8];
#pragma unroll
    for (int q = 0; q < 8; ++q) pv[q] = pk[e + 2 * q + half];
#pragma unroll
    for (int q = 0; q < 8; ++q) vi[q] = ((const u16x8*)(h0b + (size_t)pv[q].x * 256))[sub];
#pragma unroll
    for (int q = 0; q < 8; ++q){
      float w = __uint_as_float(pv[q].y);
#pragma unroll
      for (int j = 0; j < 8; ++j) acc[j] = fmaf(w, b2f(vi[q][j]), acc[j]);
    }
  }
  for (; e + 8 <= e1; e += 8){
    uint2 pv[4]; u16x8 vi[4];
#pragma unroll
    for (int q = 0; q < 4; ++q) pv[q] = pk[e + 2 * q + half];
#pragma unroll
    for (int q = 0; q < 4; ++q) vi[q] = ((const u16x8*)(h0b + (size_t)pv[q].x * 256))[sub];
#pragma unroll
    for (int q = 0; q < 4; ++q){
      float w = __uint_as_float(pv[q].y);
#pragma unroll
      for (int j = 0; j < 8; ++j) acc[j] = fmaf(w, b2f(vi[q][j]), acc[j]);
    }
  }
  for (; e < e1; e += 2){
    int ee = e + half;
    if (ee < e1){
      uint2 p = pk[ee];
      float w = __uint_as_float(p.y);
      u16x8 v = ((const u16x8*)(h0b + (size_t)p.x * 256))[sub];
#pragma unroll
      for (int j = 0; j < 8; ++j) acc[j] = fmaf(w, b2f(v[j]), acc[j]);
    }
  }
#pragma unroll
  for (int j = 0; j < 8; ++j) acc[j] += __shfl_xor(acc[j], 32);
  const float4* bp = (const float4*)b1;
  float4 bb0 = bp[sub * 2], bb1 = bp[sub * 2 + 1];
  float bv[8] = {bb0.x, bb0.y, bb0.z, bb0.w, bb1.x, bb1.y, bb1.z, bb1.w};
  u16x8 o;
#pragma unroll
  for (int j = 0; j < 8; ++j) o[j] = f2b(fmaxf(fmaf(acc[j], dr, bv[j]), 0.f));
  if (half == 0) ((u16x8*)(h1b + (size_t)r * 256))[sub] = o;
}

// ---------------- Cheb spmm v3: half-wave, 16-edge unroll ----------------
__global__ __launch_bounds__(256) void k_cheb_spmm2(
    const unsigned short* __restrict__ Ck, int ckstride,
    const unsigned short* __restrict__ sub16, int substride,
    const float* __restrict__ subf,
    const unsigned short* __restrict__ srcb, int sstride,
    float* __restrict__ dst, unsigned short* __restrict__ dstb,
    const uint2* __restrict__ pk, const int* __restrict__ row_ptr,
    const float* __restrict__ dis2, float coef, int N){
  int lane = threadIdx.x & 63;
  int r = blockIdx.x * 4 + (threadIdx.x >> 6);
  if (r >= N) return;
  int half = lane >> 5;
  int sub  = lane & 31;              // cols sub*4 .. sub*4+3
  float a0 = 0.f, a1 = 0.f, a2 = 0.f, a3 = 0.f;
  int e0 = row_ptr[r], e1 = row_ptr[r + 1];
  int e = e0;
  for (; e + 16 <= e1; e += 16){
    uint2 pv[8]; uint2 vi[8];
#pragma unroll
    for (int q = 0; q < 8; ++q) pv[q] = pk[e + 2 * q + half];
#pragma unroll
    for (int q = 0; q < 8; ++q) vi[q] = ((const uint2*)(srcb + (size_t)pv[q].x * sstride))[sub];
#pragma unroll
    for (int q = 0; q < 8; ++q){
      float w = __uint_as_float(pv[q].y);
      a0 = fmaf(w, b2f_lo(vi[q].x), a0);
      a1 = fmaf(w, b2f_hi(vi[q].x), a1);
      a2 = fmaf(w, b2f_lo(vi[q].y), a2);
      a3 = fmaf(w, b2f_hi(vi[q].y), a3);
    }
  }
  for (; e + 8 <= e1; e += 8){
    uint2 pv[4]; uint2 vi[4];
#pragma unroll
    for (int q = 0; q < 4; ++q) pv[q] = pk[e + 2 * q + half];
#pragma unroll
    for (int q = 0; q < 4; ++q) vi[q] = ((const uint2*)(srcb + (size_t)pv[q].x * sstride))[sub];
#pragma unroll
    for (int q = 0; q < 4; ++q){
      float w = __uint_as_float(pv[q].y);
      a0 = fmaf(w, b2f_lo(vi[q].x), a0);
      a1 = fmaf(w, b2f_hi(vi[q].x), a1);
      a2 = fmaf(w, b2f_lo(vi[q].y), a2);
      a3 = fmaf(w, b2f_hi(vi[q].y), a3);
    }
  }
  for (; e < e1; e += 2){
    int ee = e + half;
    if (ee < e1){
      uint2 p = pk[ee];
      float w = __uint_as_float(p.y);
      uint2 v = ((const uint2*)(srcb + (size_t)p.x * sstride))[sub];
      a0 = fmaf(w, b2f_lo(v.x), a0);
      a1 = fmaf(w, b2f_hi(v.x), a1);
      a2 = fmaf(w, b2f_lo(v.y), a2);
      a3 = fmaf(w, b2f_hi(v.y), a3);
    }
  }
  a0 += __shfl_xor(a0, 32); a1 += __shfl_xor(a1, 32);
  a2 += __shfl_xor(a2, 32); a3 += __shfl_xor(a3, 32);
  float c = coef * dis2[r];
  uint2 ckv = ((const uint2*)(Ck + (size_t)r * ckstride))[sub];
  float r0 = fmaf(c, a0, b2f_lo(ckv.x));
  float r1 = fmaf(c, a1, b2f_hi(ckv.x));
  float r2 = fmaf(c, a2, b2f_lo(ckv.y));
  float r3 = fmaf(c, a3, b2f_hi(ckv.y));
  if (sub16){
    uint2 sv = ((const uint2*)(sub16 + (size_t)r * substride))[sub];
    r0 -= b2f_lo(sv.x); r1 -= b2f_hi(sv.x);
    r2 -= b2f_lo(sv.y); r3 -= b2f_hi(sv.y);
  }
  if (subf){
    float4 s4 = ((const float4*)(subf + (size_t)r * 128))[sub];
    r0 -= s4.x; r1 -= s4.y; r2 -= s4.z; r3 -= s4.w;
  }
  if (half == 0){
    ((float4*)(dst + (size_t)r * 128))[sub] = make_float4(r0, r1, r2, r3);
    if (dstb){
      uint2 pkd;
      pkd.x = (unsigned)f2b(r0) | ((unsigned)f2b(r1) << 16);
      pkd.y = (unsigned)f2b(r2) | ((unsigned)f2b(r3) << 16);
      ((uint2*)(dstb + (size_t)r * 128))[sub] = pkd;
    }
  }
}

// ---------------- final spmm fused with feat epilogue (half-wave, 16-edge unroll) ----------------
__global__ __launch_bounds__(256) void k_spmm_final(
    const unsigned short* __restrict__ Ck, int ckstride,
    const float* __restrict__ subf,
    const unsigned short* __restrict__ srcb, int sstride,
    const float* __restrict__ bc, const float* __restrict__ W_out, const float* __restrict__ W_root,
    float* __restrict__ feat, float* __restrict__ p, float* __restrict__ wr,
    const uint2* __restrict__ pk, const int* __restrict__ row_ptr,
    const float* __restrict__ dis2, float coef, int N){
  int lane = threadIdx.x & 63;
  int r = blockIdx.x * 4 + (threadIdx.x >> 6);
  if (r >= N) return;
  int half = lane >> 5;
  int sub  = lane & 31;
  float a0 = 0.f, a1 = 0.f, a2 = 0.f, a3 = 0.f;
  int e0 = row_ptr[r], e1 = row_ptr[r + 1];
  int e = e0;
  for (; e + 16 <= e1; e += 16){
    uint2 pv[8]; uint2 vi[8];
#pragma unroll
    for (int q = 0; q < 8; ++q) pv[q] = pk[e + 2 * q + half];
#pragma unroll
    for (int q = 0; q < 8; ++q) vi[q] = ((const uint2*)(srcb + (size_t)pv[q].x * sstride))[sub];
#pragma unroll
    for (int q = 0; q < 8; ++q){
      float w = __uint_as_float(pv[q].y);
      a0 = fmaf(w, b2f_lo(vi[q].x), a0);
      a1 = fmaf(w, b2f_hi(vi[q].x), a1);
      a2 = fmaf(w, b2f_lo(vi[q].y), a2);
      a3 = fmaf(w, b2f_hi(vi[q].y), a3);
    }
  }
  for (; e + 8 <= e1; e += 8){
    uint2 pv[4]; uint2 vi[4];
#pragma unroll
    for (int q = 0; q < 4; ++q) pv[q] = pk[e + 2 * q + half];
#pragma unroll
    for (int q = 0; q < 4; ++q) vi[q] = ((const uint2*)(srcb + (size_t)pv[q].x * sstride))[sub];
#pragma unroll
    for (int q = 0; q < 4; ++q){
      float w = __uint_as_float(pv[q].y);
      a0 = fmaf(w, b2f_lo(vi[q].x), a0);
      a1 = fmaf(w, b2f_hi(vi[q].x), a1);
      a2 = fmaf(w, b2f_lo(vi[q].y), a2);
      a3 = fmaf(w, b2f_hi(vi[q].y), a3);
    }
  }
  for (; e < e1; e += 2){
    int ee = e + half;
    if (ee < e1){
      uint2 pp = pk[ee];
      float w = __uint_as_float(pp.y);
      uint2 v = ((const uint2*)(srcb + (size_t)pp.x * sstride))[sub];
      a0 = fmaf(w, b2f_lo(v.x), a0);
      a1 = fmaf(w, b2f_hi(v.x), a1);
      a2 = fmaf(w, b2f_lo(v.y), a2);
      a3 = fmaf(w, b2f_hi(v.y), a3);
    }
  }
  a0 += __shfl_xor(a0, 32); a1 += __shfl_xor(a1, 32);
  a2 += __shfl_xor(a2, 32); a3 += __shfl_xor(a3, 32);
  float c = coef * dis2[r];
  uint2 ckv = ((const uint2*)(Ck + (size_t)r * ckstride))[sub];
  float r0 = fmaf(c, a0, b2f_lo(ckv.x));
  float r1 = fmaf(c, a1, b2f_hi(ckv.x));
  float r2 = fmaf(c, a2, b2f_lo(ckv.y));
  float r3 = fmaf(c, a3, b2f_hi(ckv.y));
  float4 s4 = ((const float4*)(subf + (size_t)r * 128))[sub];
  r0 -= s4.x; r1 -= s4.y; r2 -= s4.z; r3 -= s4.w;
  float4 bb = ((const float4*)bc)[sub];
  r0 = fmaxf(r0 + bb.x, 0.f);
  r1 = fmaxf(r1 + bb.y, 0.f);
  r2 = fmaxf(r2 + bb.z, 0.f);
  r3 = fmaxf(r3 + bb.w, 0.f);
  if (half == 0)
    ((float4*)(feat + (size_t)r * 128))[sub] = make_float4(r0, r1, r2, r3);
  float4 wo = ((const float4*)W_out)[sub];
  float4 wrt = ((const float4*)W_root)[sub];
  float pp2 = r0 * wo.x + r1 * wo.y + r2 * wo.z + r3 * wo.w;
  float rr  = r0 * wrt.x + r1 * wrt.y + r2 * wrt.z + r3 * wrt.w;
#pragma unroll
  for (int off = 1; off < 32; off <<= 1){
    pp2 += __shfl_xor(pp2, off);
    rr  += __shfl_xor(rr, off);
  }
  if (lane == 0){ p[r] = pp2; wr[r] = rr; }
}

// ---------------- ClusterGCN output (8-wide, packed edges) ----------------
__global__ __launch_bounds__(256) void k_out(const float* __restrict__ p, const float* __restrict__ wr,
    const float* __restrict__ invw, const uint2* __restrict__ pk, const int* __restrict__ row_ptr,
    const float* __restrict__ b3, float* __restrict__ out, int N){
  int r = blockIdx.x * 256 + threadIdx.x;
  if (r >= N) return;
  float s = p[r];
  int e0 = row_ptr[r], e1 = row_ptr[r + 1];
  int e = e0;
  float acc[8] = {0.f,0.f,0.f,0.f,0.f,0.f,0.f,0.f};
  for (; e + 8 <= e1; e += 8){
    int si[8];
#pragma unroll
    for (int q = 0; q < 8; ++q) si[q] = (int)pk[e + q].x;
#pragma unroll
    for (int q = 0; q < 8; ++q) acc[q] += p[si[q]];
  }
  for (; e < e1; ++e) acc[0] += p[(int)pk[e].x];
  s += ((acc[0]+acc[1])+(acc[2]+acc[3])) + ((acc[4]+acc[5])+(acc[6]+acc[7]));
  out[r] = invw[r] * s + wr[r] + b3[0];
}

extern "C" void kernel_launch(void* const* d_in, const int* in_sizes, int n_in,
                              void* d_out, int out_size, void* d_ws, size_t ws_size,
                              hipStream_t stream){
  const float* x      = (const float*)d_in[0];
  const void*  ei     = d_in[1];
  const float* ew     = (const float*)d_in[2];
  const float* W1     = (const float*)d_in[3];
  const float* b1     = (const float*)d_in[4];
  const float* Wc     = (const float*)d_in[5];
  const float* bc     = (const float*)d_in[6];
  const float* W_out  = (const float*)d_in[7];
  const float* W_root = (const float*)d_in[8];
  const float* b3     = (const float*)d_in[9];
  const int N = in_sizes[0] / 512;
  const int E = in_sizes[2];

  char* w = (char*)d_ws;
  auto alloc = [&](size_t bytes)->void*{ void* r = (void*)w; w += (bytes + 255) & ~(size_t)255; return r; };
  unsigned short* h1b = (unsigned short*)alloc((size_t)N * 256 * 2 * 2);
  float* B0 = (float*)h1b;
  float* B1 = B0 + (size_t)N * 128;
  float* B2 = (float*)alloc((size_t)N * 128 * 4);
  unsigned short* C5c = (unsigned short*)B2;
  unsigned short* CC  = (unsigned short*)alloc((size_t)N * 768 * 2);
  unsigned short* h0b = (unsigned short*)alloc((size_t)N * 256 * 2);
  unsigned short* Bb0 = h0b;
  unsigned short* Bb1 = h0b + (size_t)N * 128;
  uint2* csr_sw  = (uint2*)alloc((size_t)E * 8);
  uint2* pk_gcn  = (uint2*)alloc((size_t)E * 8);
  uint2* pk_cheb = (uint2*)alloc((size_t)E * 8);
  uint2* part    = (uint2*)alloc((size_t)E * 8);
  int nblk = ceil_div(E, EPB);
  int*   block_hist  = (int*)alloc((size_t)nblk * 512 * 4);
  int*   off_hist    = (int*)alloc((size_t)nblk * 512 * 4);
  int*   bucket_total= (int*)alloc(512 * 4);
  int*   bucket_base = (int*)alloc(513 * 4);
  int*   row_ptr = (int*)  alloc((size_t)(N + 1) * 4);
  float* dis1    = (float*)alloc((size_t)N * 4);
  float* dis2    = (float*)alloc((size_t)N * 4);
  float* invw    = (float*)alloc((size_t)N * 4);
  float* pbuf    = (float*)alloc((size_t)N * 4);
  float* wrbuf   = (float*)alloc((size_t)N * 4);
  short* W1t_h   = (short*)alloc((size_t)512 * 256 * 2);
  short* W1t_l   = (short*)alloc((size_t)512 * 256 * 2);
  short* Wct_h   = (short*)alloc((size_t)768 * 256 * 2);
  int*   flag    = (int*)  alloc(256);

  hipMemsetAsync(flag, 0, 4, stream);

  k_detect<<<16, 256, 0, stream>>>((const int*)ei, E, flag);
  k_hist<<<nblk, 256, 0, stream>>>(ei, E, flag, block_hist);
  k_colscan<<<512, 64, 0, stream>>>(block_hist, off_hist, bucket_total, nblk);
  k_bucketbase<<<1, 512, 0, stream>>>(bucket_total, bucket_base, row_ptr, N, E);
  k_partition<<<nblk, 256, 0, stream>>>(ei, ew, E, flag, off_hist, bucket_base, part);
  int nbkt = ceil_div(N, 256);
  k_bucket_csr<<<nbkt, 256, 0, stream>>>(part, bucket_base, csr_sw, row_ptr, dis1, dis2, invw, N);
  k_norm<<<ceil_div(E, 256), 256, 0, stream>>>(csr_sw, dis1, dis2, pk_gcn, pk_cheb, E);

  k_prep_w<<<ceil_div(512 * 256, 256), 256, 0, stream>>>(W1, W1t_h, W1t_l, 512, 256);
  k_prep_wc<<<ceil_div(768 * 256, 256), 256, 0, stream>>>(Wc, Wct_h);

  // ---- GCNConv ----
  int nbm = ceil_div(N, 128);
  int grid1 = 8 * 2 * ceil_div(nbm, 8);
  k_gemm_mfma<<<grid1, 256, 0, stream>>>(x, W1t_h, W1t_l, h0b, N, 256, 512, nbm);
  k_gcn_agg<<<ceil_div(N, 4), 256, 0, stream>>>(h0b, pk_gcn, row_ptr, dis1, b1, h1b, N);

  // ---- fused Cheb projection ----
  int grid2 = 8 * 6 * ceil_div(nbm, 8);
  k_gemm_mfma2<<<grid2, 256, 0, stream>>>(h1b, Wct_h, CC, C5c, N, 768, 256, nbm);

  // ---- Clenshaw ----
  auto spmm = [&](const unsigned short* Ck, const unsigned short* s16, int s16s, const float* sf,
                  const unsigned short* src, int ss, float* dst, unsigned short* dstb, float coef){
    k_cheb_spmm2<<<ceil_div(N, 4), 256, 0, stream>>>(Ck, 768, s16, s16s, sf, src, ss, dst, dstb,
        pk_cheb, row_ptr, dis2, coef, N);
  };
  spmm(CC + 4*128, nullptr, 0, nullptr, C5c, 128, B0, Bb0, -2.f);
  spmm(CC + 3*128, C5c, 128, nullptr, Bb0, 128, B1, Bb1, -2.f);
  spmm(CC + 2*128, nullptr, 0, B0, Bb1, 128, B2, Bb0, -2.f);
  spmm(CC + 1*128, nullptr, 0, B1, Bb0, 128, B0, Bb1, -2.f);

  // ---- final ----
  float* out  = (float*)d_out;
  float* feat = out + N;
  k_spmm_final<<<ceil_div(N, 4), 256, 0, stream>>>(CC + 0*128, 768, B2, Bb1, 128,
      bc, W_out, W_root, feat, pbuf, wrbuf, pk_cheb, row_ptr, dis2, -1.f, N);
  k_out<<<ceil_div(N, 256), 256, 0, stream>>>(pbuf, wrbuf, invw, pk_cheb, row_ptr, b3, out, N);
}

// Round 16
// 855.374 us; speedup vs baseline: 1.0131x; 1.0131x over previous
//
#include <hip/hip_runtime.h>
#include <cstdint>
#include <cstddef>

typedef __attribute__((ext_vector_type(8))) short bf16x8;
typedef __attribute__((ext_vector_type(8))) unsigned short u16x8;
typedef __attribute__((ext_vector_type(4))) float f32x4;

static inline int ceil_div(int a, int b){ return (a + b - 1) / b; }

__device__ inline unsigned short f2b(float f){            // fp32 -> bf16 (RNE)
  unsigned u = __float_as_uint(f);
  unsigned r = u + 0x7FFFu + ((u >> 16) & 1u);
  return (unsigned short)(r >> 16);
}
__device__ inline float b2f(unsigned short s){
  return __uint_as_float((unsigned)s << 16);
}
__device__ inline float b2f_lo(unsigned v){ return __uint_as_float(v << 16); }
__device__ inline float b2f_hi(unsigned v){ return __uint_as_float(v & 0xFFFF0000u); }

#define EPB 4096   // edges per histogram/partition block

// ---------------- dtype detection (int64 vs int32 edge_index) ----------------
__global__ __launch_bounds__(256) void k_detect(const int* __restrict__ ei32, int E, int* __restrict__ flag){
  int t = blockIdx.x * 256 + threadIdx.x;
  if (t < 4096) {
    long long idx = 2LL * t + 1;
    if (idx < 2LL * E && ei32[idx] != 0) atomicOr(flag, 1);
  }
}

// ---------------- CSR build: counting sort by dst bucket (dst>>8) ----------------
__global__ __launch_bounds__(256) void k_hist(const void* __restrict__ ei, int E,
                                              const int* __restrict__ flag, int* __restrict__ block_hist){
  __shared__ int h[512];
  for (int i = threadIdx.x; i < 512; i += 256) h[i] = 0;
  __syncthreads();
  int base = blockIdx.x * EPB;
  bool is32 = (*flag != 0);
  for (int i = 0; i < 16; ++i){
    int e = base + i * 256 + threadIdx.x;
    if (e < E){
      int dst = is32 ? ((const int*)ei)[(size_t)E + e] : (int)((const long long*)ei)[(size_t)E + e];
      atomicAdd(&h[dst >> 8], 1);
    }
  }
  __syncthreads();
  for (int i = threadIdx.x; i < 512; i += 256) block_hist[blockIdx.x * 512 + i] = h[i];
}

__global__ __launch_bounds__(64) void k_colscan(const int* __restrict__ block_hist, int* __restrict__ off_hist,
                                                int* __restrict__ bucket_total, int nblk){
  int k = blockIdx.x;
  int lane = threadIdx.x;
  int carry = 0;
  for (int c = 0; c * 64 < nblk; ++c){
    int b = c * 64 + lane;
    int v = (b < nblk) ? block_hist[b * 512 + k] : 0;
    int inc = v;
#pragma unroll
    for (int off = 1; off < 64; off <<= 1){
      int u = __shfl_up(inc, off);
      if (lane >= off) inc += u;
    }
    if (b < nblk) off_hist[b * 512 + k] = carry + inc - v;
    carry += __shfl(inc, 63);
  }
  if (lane == 0) bucket_total[k] = carry;
}

__global__ __launch_bounds__(512) void k_bucketbase(const int* __restrict__ bucket_total,
                                                    int* __restrict__ bucket_base,
                                                    int* __restrict__ row_ptr, int N, int E){
  __shared__ int sh[512];
  int t = threadIdx.x;
  int v = bucket_total[t];
  sh[t] = v; __syncthreads();
  for (int off = 1; off < 512; off <<= 1){
    int u = (t >= off) ? sh[t - off] : 0;
    __syncthreads();
    sh[t] += u;
    __syncthreads();
  }
  bucket_base[t] = sh[t] - v;
  if (t == 511) bucket_base[512] = sh[511];
  if (t == 0) row_ptr[N] = E;
}

__global__ __launch_bounds__(256) void k_partition(const void* __restrict__ ei, const float* __restrict__ ew,
                                                   int E, const int* __restrict__ flag,
                                                   const int* __restrict__ off_hist,
                                                   const int* __restrict__ bucket_base,
                                                   uint2* __restrict__ part){
  __shared__ int cur[512];
  for (int i = threadIdx.x; i < 512; i += 256)
    cur[i] = off_hist[blockIdx.x * 512 + i] + bucket_base[i];
  __syncthreads();
  int base = blockIdx.x * EPB;
  bool is32 = (*flag != 0);
  for (int i = 0; i < 16; ++i){
    int e = base + i * 256 + threadIdx.x;
    if (e < E){
      int src, dst;
      if (is32){ src = ((const int*)ei)[e]; dst = ((const int*)ei)[(size_t)E + e]; }
      else     { src = (int)((const long long*)ei)[e]; dst = (int)((const long long*)ei)[(size_t)E + e]; }
      int pos = atomicAdd(&cur[dst >> 8], 1);
      part[pos] = make_uint2((unsigned)src | ((unsigned)(dst & 255) << 20), __float_as_uint(ew[e]));
    }
  }
}

__global__ __launch_bounds__(256) void k_bucket_csr(const uint2* __restrict__ part,
                                                    const int* __restrict__ bucket_base,
                                                    uint2* __restrict__ csr_sw, int* __restrict__ row_ptr,
                                                    float* __restrict__ dis1, float* __restrict__ dis2,
                                                    float* __restrict__ invw, int N){
  __shared__ int cnt[256];
  __shared__ float wsum[256];
  __shared__ int cursor[256];
  __shared__ int ws[4];
  int k = blockIdx.x;
  int t = threadIdx.x;
  int base = bucket_base[k], end = bucket_base[k + 1];
  cnt[t] = 0; wsum[t] = 0.f;
  __syncthreads();
  for (int i = base + t; i < end; i += 256){
    uint2 rec = part[i];
    int dstl = (rec.x >> 20) & 255;
    atomicAdd(&cnt[dstl], 1);
    atomicAdd(&wsum[dstl], __uint_as_float(rec.y));
  }
  __syncthreads();
  int v = cnt[t];
  int lane = t & 63;
  int inc = v;
#pragma unroll
  for (int off = 1; off < 64; off <<= 1){
    int u = __shfl_up(inc, off);
    if (lane >= off) inc += u;
  }
  if (lane == 63) ws[t >> 6] = inc;
  __syncthreads();
  int woff = 0;
  for (int i = 0; i < (t >> 6); ++i) woff += ws[i];
  int exc = woff + inc - v;
  int node = k * 256 + t;
  if (node < N){
    row_ptr[node] = base + exc;
    float s = wsum[t];
    dis1[node] = rsqrtf(s + 1.0f);
    dis2[node] = (s > 0.f) ? rsqrtf(s) : 0.f;
    invw[node] = 1.0f / (float)(v + 1);
  }
  cursor[t] = exc;
  __syncthreads();
  for (int i = base + t; i < end; i += 256){
    uint2 rec = part[i];
    int dstl = (rec.x >> 20) & 255;
    int pos = base + atomicAdd(&cursor[dstl], 1);
    csr_sw[pos] = make_uint2(rec.x & 0xFFFFFu, rec.y);
  }
}

// ---------------- edge norms: packed (src, w) streams for gcn and cheb ----------------
__global__ __launch_bounds__(256) void k_norm(const uint2* __restrict__ csr_sw,
                                              const float* __restrict__ dis1, const float* __restrict__ dis2,
                                              uint2* __restrict__ pk_gcn, uint2* __restrict__ pk_cheb, int E){
  int e = blockIdx.x * 256 + threadIdx.x;
  if (e >= E) return;
  uint2 p = csr_sw[e];
  int s = (int)p.x;
  float w = __uint_as_float(p.y);
  pk_gcn[e]  = make_uint2(p.x, __float_as_uint(w * dis1[s]));
  pk_cheb[e] = make_uint2(p.x, __float_as_uint(w * dis2[s]));
}

// ---------------- weight prep: W1 [512][256] fp32 -> [256][512] bf16 ----------------
__global__ __launch_bounds__(256) void k_prep_w1(const float* __restrict__ W, short* __restrict__ Wh){
  int idx = blockIdx.x * 256 + threadIdx.x;
  if (idx >= 512 * 256) return;
  int n = idx >> 9, k = idx & 511;
  Wh[idx] = (short)f2b(W[(size_t)k * 256 + n]);
}

__global__ __launch_bounds__(256) void k_prep_wc(const float* __restrict__ Wc, short* __restrict__ Wh){
  int idx = blockIdx.x * 256 + threadIdx.x;
  if (idx >= 768 * 256) return;
  int n = idx >> 8, k = idx & 255;
  Wh[idx] = (short)f2b(Wc[(size_t)(n >> 7) * 256 * 128 + (size_t)k * 128 + (n & 127)]);
}

// ---------------- MFMA GEMM 1: A = bf16(x), B = bf16(W1); single term; A reg-prefetch; XCD swizzle ----
__global__ __launch_bounds__(256) void k_gemm_mfma(
    const float* __restrict__ A,
    const short* __restrict__ Bh,
    unsigned short* __restrict__ Cb,
    int M, int Ncols, int K, int nbm)
{
  __shared__ short Ah[128][40];
  __shared__ short Bhs[128][40];
  int bid = blockIdx.x;
  int g = bid & 7, j = bid >> 3;
  int m_tile = g + 8 * (j >> 1);
  int n_tile = j & 1;
  if (m_tile >= nbm) return;
  int m0 = m_tile * 128, n0 = n_tile * 128;
  int t = threadIdx.x;
  int lane = t & 63, wid = t >> 6;
  int wr = wid >> 1, wc = wid & 1;
  int fr = lane & 15, fq = lane >> 4;
  int srow = t >> 1, skh = (t & 1) << 4;

  f32x4 acc[4][4];
#pragma unroll
  for (int i = 0; i < 4; ++i)
#pragma unroll
    for (int jj = 0; jj < 4; ++jj) acc[i][jj] = (f32x4){0.f, 0.f, 0.f, 0.f};

  bool aval = (m0 + srow) < M;
  const float* Aptr = A + (size_t)(m0 + srow) * K + skh;
  const short* Bhp = Bh + (size_t)(n0 + srow) * K + skh;

  float4 a0, a1, a2, a3;
  if (aval){
    const float4* ap = (const float4*)Aptr;
    a0 = ap[0]; a1 = ap[1]; a2 = ap[2]; a3 = ap[3];
  } else a0 = a1 = a2 = a3 = make_float4(0.f, 0.f, 0.f, 0.f);

  for (int k0 = 0; k0 < K; k0 += 32){
    bf16x8 h0, h1;
    h0[0]=(short)f2b(a0.x); h0[1]=(short)f2b(a0.y); h0[2]=(short)f2b(a0.z); h0[3]=(short)f2b(a0.w);
    h0[4]=(short)f2b(a1.x); h0[5]=(short)f2b(a1.y); h0[6]=(short)f2b(a1.z); h0[7]=(short)f2b(a1.w);
    h1[0]=(short)f2b(a2.x); h1[1]=(short)f2b(a2.y); h1[2]=(short)f2b(a2.z); h1[3]=(short)f2b(a2.w);
    h1[4]=(short)f2b(a3.x); h1[5]=(short)f2b(a3.y); h1[6]=(short)f2b(a3.z); h1[7]=(short)f2b(a3.w);
    *(bf16x8*)&Ah[srow][skh]     = h0;
    *(bf16x8*)&Ah[srow][skh + 8] = h1;
    {
      const bf16x8* bp = (const bf16x8*)(Bhp + k0);
      *(bf16x8*)&Bhs[srow][skh]     = bp[0];
      *(bf16x8*)&Bhs[srow][skh + 8] = bp[1];
    }
    __syncthreads();
    bool more = (k0 + 32) < K;
    float4 n0v, n1v, n2v, n3v;
    if (more && aval){
      const float4* ap = (const float4*)(Aptr + k0 + 32);
      n0v = ap[0]; n1v = ap[1]; n2v = ap[2]; n3v = ap[3];
    } else n0v = n1v = n2v = n3v = make_float4(0.f, 0.f, 0.f, 0.f);
    bf16x8 afh[4], bfh[4];
#pragma unroll
    for (int m = 0; m < 4; ++m){
      int r = wr * 64 + m * 16 + fr;
      afh[m] = *(const bf16x8*)&Ah[r][fq * 8];
    }
#pragma unroll
    for (int n = 0; n < 4; ++n){
      int r = wc * 64 + n * 16 + fr;
      bfh[n] = *(const bf16x8*)&Bhs[r][fq * 8];
    }
#pragma unroll
    for (int m = 0; m < 4; ++m)
#pragma unroll
      for (int n = 0; n < 4; ++n){
        acc[m][n] = __builtin_amdgcn_mfma_f32_16x16x32_bf16(afh[m], bfh[n], acc[m][n], 0, 0, 0);
      }
    __syncthreads();
    a0 = n0v; a1 = n1v; a2 = n2v; a3 = n3v;
  }
#pragma unroll
  for (int m = 0; m < 4; ++m){
#pragma unroll
    for (int n = 0; n < 4; ++n){
      int col = n0 + wc * 64 + n * 16 + fr;
#pragma unroll
      for (int r = 0; r < 4; ++r){
        int row = m0 + wr * 64 + m * 16 + fq * 4 + r;
        if (row < M){
          Cb[(size_t)row * Ncols + col] = f2b(acc[m][n][r]);
        }
      }
    }
  }
}

// ---------------- MFMA GEMM 2: A = bf16(h1), B = bf16(Wc); single term; reg-prefetch; XCD swizzle ----
__global__ __launch_bounds__(256) void k_gemm_mfma2(
    const unsigned short* __restrict__ Ahg,
    const short* __restrict__ Bh,
    unsigned short* __restrict__ Cb, unsigned short* __restrict__ C5c,
    int M, int Ncols, int K, int nbm)
{
  __shared__ short Ah[128][40];
  __shared__ short Bhs[128][40];
  int bid = blockIdx.x;
  int g = bid & 7, j = bid >> 3;
  int m_tile = g + 8 * (j / 6);
  int n_tile = j - 6 * (j / 6);
  if (m_tile >= nbm) return;
  int m0 = m_tile * 128, n0 = n_tile * 128;
  int t = threadIdx.x;
  int lane = t & 63, wid = t >> 6;
  int wr = wid >> 1, wc = wid & 1;
  int fr = lane & 15, fq = lane >> 4;
  int srow = t >> 1, skh = (t & 1) << 4;

  f32x4 acc[4][4];
#pragma unroll
  for (int i = 0; i < 4; ++i)
#pragma unroll
    for (int jj = 0; jj < 4; ++jj) acc[i][jj] = (f32x4){0.f, 0.f, 0.f, 0.f};

  bool aval = (m0 + srow) < M;
  const unsigned short* Ahp = Ahg + (size_t)(m0 + srow) * K + skh;
  const short* Bhp = Bh + (size_t)(n0 + srow) * K + skh;

  bf16x8 ch0, ch1;
  if (aval){
    const bf16x8* ah = (const bf16x8*)Ahp;
    ch0 = ah[0]; ch1 = ah[1];
  } else {
    bf16x8 z = (bf16x8){0,0,0,0,0,0,0,0};
    ch0 = ch1 = z;
  }

  for (int k0 = 0; k0 < K; k0 += 32){
    *(bf16x8*)&Ah[srow][skh]     = ch0;
    *(bf16x8*)&Ah[srow][skh + 8] = ch1;
    {
      const bf16x8* bp = (const bf16x8*)(Bhp + k0);
      *(bf16x8*)&Bhs[srow][skh]     = bp[0];
      *(bf16x8*)&Bhs[srow][skh + 8] = bp[1];
    }
    __syncthreads();
    bool more = (k0 + 32) < K;
    bf16x8 nh0, nh1;
    if (more && aval){
      const bf16x8* ah = (const bf16x8*)(Ahp + k0 + 32);
      nh0 = ah[0]; nh1 = ah[1];
    } else {
      bf16x8 z = (bf16x8){0,0,0,0,0,0,0,0};
      nh0 = nh1 = z;
    }
    bf16x8 afh[4], bfh[4];
#pragma unroll
    for (int m = 0; m < 4; ++m){
      int r = wr * 64 + m * 16 + fr;
      afh[m] = *(const bf16x8*)&Ah[r][fq * 8];
    }
#pragma unroll
    for (int n = 0; n < 4; ++n){
      int r = wc * 64 + n * 16 + fr;
      bfh[n] = *(const bf16x8*)&Bhs[r][fq * 8];
    }
#pragma unroll
    for (int m = 0; m < 4; ++m)
#pragma unroll
      for (int n = 0; n < 4; ++n){
        acc[m][n] = __builtin_amdgcn_mfma_f32_16x16x32_bf16(afh[m], bfh[n], acc[m][n], 0, 0, 0);
      }
    __syncthreads();
    ch0 = nh0; ch1 = nh1;
  }
#pragma unroll
  for (int m = 0; m < 4; ++m){
#pragma unroll
    for (int n = 0; n < 4; ++n){
      int col = n0 + wc * 64 + n * 16 + fr;
#pragma unroll
      for (int r = 0; r < 4; ++r){
        int row = m0 + wr * 64 + m * 16 + fq * 4 + r;
        if (row < M){
          unsigned short v = f2b(acc[m][n][r]);
          Cb[(size_t)row * Ncols + col] = v;
          if (n_tile == 5) C5c[(size_t)row * 128 + (col - 640)] = v;
        }
      }
    }
  }
}

// ---------------- GCN aggregation: half-wave, 16B/lane gathers ----------------
__global__ __launch_bounds__(256) void k_gcn_agg(
    const unsigned short* __restrict__ h0b,
    const uint2* __restrict__ pk, const int* __restrict__ row_ptr,
    const float* __restrict__ dis1, const float* __restrict__ b1,
    unsigned short* __restrict__ h1b, int N){
  int lane = threadIdx.x & 63;
  int r = blockIdx.x * 4 + (threadIdx.x >> 6);
  if (r >= N) return;
  int half = lane >> 5;
  int sub  = lane & 31;
  float dr = dis1[r];
  u16x8 sv = ((const u16x8*)(h0b + (size_t)r * 256))[sub];
  float hsc = (half == 0) ? dr : 0.f;
  float acc[8];
#pragma unroll
  for (int j = 0; j < 8; ++j) acc[j] = hsc * b2f(sv[j]);
  int e0 = row_ptr[r], e1 = row_ptr[r + 1];
  int e = e0;
  for (; e + 8 <= e1; e += 8){
    uint2 pv[4]; u16x8 vi[4];
#pragma unroll
    for (int q = 0; q < 4; ++q) pv[q] = pk[e + 2 * q + half];
#pragma unroll
    for (int q = 0; q < 4; ++q) vi[q] = ((const u16x8*)(h0b + (size_t)pv[q].x * 256))[sub];
#pragma unroll
    for (int q = 0; q < 4; ++q){
      float w = __uint_as_float(pv[q].y);
#pragma unroll
      for (int j = 0; j < 8; ++j) acc[j] = fmaf(w, b2f(vi[q][j]), acc[j]);
    }
  }
  for (; e < e1; e += 2){
    int ee = e + half;
    if (ee < e1){
      uint2 p = pk[ee];
      float w = __uint_as_float(p.y);
      u16x8 v = ((const u16x8*)(h0b + (size_t)p.x * 256))[sub];
#pragma unroll
      for (int j = 0; j < 8; ++j) acc[j] = fmaf(w, b2f(v[j]), acc[j]);
    }
  }
#pragma unroll
  for (int j = 0; j < 8; ++j) acc[j] += __shfl_xor(acc[j], 32);
  const float4* bp = (const float4*)b1;
  float4 bb0 = bp[sub * 2], bb1 = bp[sub * 2 + 1];
  float bv[8] = {bb0.x, bb0.y, bb0.z, bb0.w, bb1.x, bb1.y, bb1.z, bb1.w};
  u16x8 o;
#pragma unroll
  for (int j = 0; j < 8; ++j) o[j] = f2b(fmaxf(fmaf(acc[j], dr, bv[j]), 0.f));
  if (half == 0) ((u16x8*)(h1b + (size_t)r * 256))[sub] = o;
}

// ---------------- Cheb spmm: half-wave, 8B/lane gathers; dst (fp32) optional ----------------
__global__ __launch_bounds__(256) void k_cheb_spmm2(
    const unsigned short* __restrict__ Ck, int ckstride,
    const unsigned short* __restrict__ sub16, int substride,
    const float* __restrict__ subf,
    const unsigned short* __restrict__ srcb, int sstride,
    float* __restrict__ dst, unsigned short* __restrict__ dstb,
    const uint2* __restrict__ pk, const int* __restrict__ row_ptr,
    const float* __restrict__ dis2, float coef, int N){
  int lane = threadIdx.x & 63;
  int r = blockIdx.x * 4 + (threadIdx.x >> 6);
  if (r >= N) return;
  int half = lane >> 5;
  int sub  = lane & 31;
  float a0 = 0.f, a1 = 0.f, a2 = 0.f, a3 = 0.f;
  int e0 = row_ptr[r], e1 = row_ptr[r + 1];
  int e = e0;
  for (; e + 8 <= e1; e += 8){
    uint2 pv[4]; uint2 vi[4];
#pragma unroll
    for (int q = 0; q < 4; ++q) pv[q] = pk[e + 2 * q + half];
#pragma unroll
    for (int q = 0; q < 4; ++q) vi[q] = ((const uint2*)(srcb + (size_t)pv[q].x * sstride))[sub];
#pragma unroll
    for (int q = 0; q < 4; ++q){
      float w = __uint_as_float(pv[q].y);
      a0 = fmaf(w, b2f_lo(vi[q].x), a0);
      a1 = fmaf(w, b2f_hi(vi[q].x), a1);
      a2 = fmaf(w, b2f_lo(vi[q].y), a2);
      a3 = fmaf(w, b2f_hi(vi[q].y), a3);
    }
  }
  for (; e < e1; e += 2){
    int ee = e + half;
    if (ee < e1){
      uint2 p = pk[ee];
      float w = __uint_as_float(p.y);
      uint2 v = ((const uint2*)(srcb + (size_t)p.x * sstride))[sub];
      a0 = fmaf(w, b2f_lo(v.x), a0);
      a1 = fmaf(w, b2f_hi(v.x), a1);
      a2 = fmaf(w, b2f_lo(v.y), a2);
      a3 = fmaf(w, b2f_hi(v.y), a3);
    }
  }
  a0 += __shfl_xor(a0, 32); a1 += __shfl_xor(a1, 32);
  a2 += __shfl_xor(a2, 32); a3 += __shfl_xor(a3, 32);
  float c = coef * dis2[r];
  uint2 ckv = ((const uint2*)(Ck + (size_t)r * ckstride))[sub];
  float r0 = fmaf(c, a0, b2f_lo(ckv.x));
  float r1 = fmaf(c, a1, b2f_hi(ckv.x));
  float r2 = fmaf(c, a2, b2f_lo(ckv.y));
  float r3 = fmaf(c, a3, b2f_hi(ckv.y));
  if (sub16){
    uint2 sv = ((const uint2*)(sub16 + (size_t)r * substride))[sub];
    r0 -= b2f_lo(sv.x); r1 -= b2f_hi(sv.x);
    r2 -= b2f_lo(sv.y); r3 -= b2f_hi(sv.y);
  }
  if (subf){
    float4 s4 = ((const float4*)(subf + (size_t)r * 128))[sub];
    r0 -= s4.x; r1 -= s4.y; r2 -= s4.z; r3 -= s4.w;
  }
  if (half == 0){
    if (dst) ((float4*)(dst + (size_t)r * 128))[sub] = make_float4(r0, r1, r2, r3);
    if (dstb){
      uint2 pkd;
      pkd.x = (unsigned)f2b(r0) | ((unsigned)f2b(r1) << 16);
      pkd.y = (unsigned)f2b(r2) | ((unsigned)f2b(r3) << 16);
      ((uint2*)(dstb + (size_t)r * 128))[sub] = pkd;
    }
  }
}

// ---------------- final spmm fused with feat epilogue (half-wave) ----------------
__global__ __launch_bounds__(256) void k_spmm_final(
    const unsigned short* __restrict__ Ck, int ckstride,
    const float* __restrict__ subf,
    const unsigned short* __restrict__ srcb, int sstride,
    const float* __restrict__ bc, const float* __restrict__ W_out, const float* __restrict__ W_root,
    float* __restrict__ feat, float* __restrict__ p, float* __restrict__ wr,
    const uint2* __restrict__ pk, const int* __restrict__ row_ptr,
    const float* __restrict__ dis2, float coef, int N){
  int lane = threadIdx.x & 63;
  int r = blockIdx.x * 4 + (threadIdx.x >> 6);
  if (r >= N) return;
  int half = lane >> 5;
  int sub  = lane & 31;
  float a0 = 0.f, a1 = 0.f, a2 = 0.f, a3 = 0.f;
  int e0 = row_ptr[r], e1 = row_ptr[r + 1];
  int e = e0;
  for (; e + 8 <= e1; e += 8){
    uint2 pv[4]; uint2 vi[4];
#pragma unroll
    for (int q = 0; q < 4; ++q) pv[q] = pk[e + 2 * q + half];
#pragma unroll
    for (int q = 0; q < 4; ++q) vi[q] = ((const uint2*)(srcb + (size_t)pv[q].x * sstride))[sub];
#pragma unroll
    for (int q = 0; q < 4; ++q){
      float w = __uint_as_float(pv[q].y);
      a0 = fmaf(w, b2f_lo(vi[q].x), a0);
      a1 = fmaf(w, b2f_hi(vi[q].x), a1);
      a2 = fmaf(w, b2f_lo(vi[q].y), a2);
      a3 = fmaf(w, b2f_hi(vi[q].y), a3);
    }
  }
  for (; e < e1; e += 2){
    int ee = e + half;
    if (ee < e1){
      uint2 pp = pk[ee];
      float w = __uint_as_float(pp.y);
      uint2 v = ((const uint2*)(srcb + (size_t)pp.x * sstride))[sub];
      a0 = fmaf(w, b2f_lo(v.x), a0);
      a1 = fmaf(w, b2f_hi(v.x), a1);
      a2 = fmaf(w, b2f_lo(v.y), a2);
      a3 = fmaf(w, b2f_hi(v.y), a3);
    }
  }
  a0 += __shfl_xor(a0, 32); a1 += __shfl_xor(a1, 32);
  a2 += __shfl_xor(a2, 32); a3 += __shfl_xor(a3, 32);
  float c = coef * dis2[r];
  uint2 ckv = ((const uint2*)(Ck + (size_t)r * ckstride))[sub];
  float r0 = fmaf(c, a0, b2f_lo(ckv.x));
  float r1 = fmaf(c, a1, b2f_hi(ckv.x));
  float r2 = fmaf(c, a2, b2f_lo(ckv.y));
  float r3 = fmaf(c, a3, b2f_hi(ckv.y));
  float4 s4 = ((const float4*)(subf + (size_t)r * 128))[sub];
  r0 -= s4.x; r1 -= s4.y; r2 -= s4.z; r3 -= s4.w;
  float4 bb = ((const float4*)bc)[sub];
  r0 = fmaxf(r0 + bb.x, 0.f);
  r1 = fmaxf(r1 + bb.y, 0.f);
  r2 = fmaxf(r2 + bb.z, 0.f);
  r3 = fmaxf(r3 + bb.w, 0.f);
  if (half == 0)
    ((float4*)(feat + (size_t)r * 128))[sub] = make_float4(r0, r1, r2, r3);
  float4 wo = ((const float4*)W_out)[sub];
  float4 wrt = ((const float4*)W_root)[sub];
  float pp2 = r0 * wo.x + r1 * wo.y + r2 * wo.z + r3 * wo.w;
  float rr  = r0 * wrt.x + r1 * wrt.y + r2 * wrt.z + r3 * wrt.w;
#pragma unroll
  for (int off = 1; off < 32; off <<= 1){
    pp2 += __shfl_xor(pp2, off);
    rr  += __shfl_xor(rr, off);
  }
  if (lane == 0){ p[r] = pp2; wr[r] = rr; }
}

// ---------------- ClusterGCN output (8-wide, packed edges) ----------------
__global__ __launch_bounds__(256) void k_out(const float* __restrict__ p, const float* __restrict__ wr,
    const float* __restrict__ invw, const uint2* __restrict__ pk, const int* __restrict__ row_ptr,
    const float* __restrict__ b3, float* __restrict__ out, int N){
  int r = blockIdx.x * 256 + threadIdx.x;
  if (r >= N) return;
  float s = p[r];
  int e0 = row_ptr[r], e1 = row_ptr[r + 1];
  int e = e0;
  float acc[8] = {0.f,0.f,0.f,0.f,0.f,0.f,0.f,0.f};
  for (; e + 8 <= e1; e += 8){
    int si[8];
#pragma unroll
    for (int q = 0; q < 8; ++q) si[q] = (int)pk[e + q].x;
#pragma unroll
    for (int q = 0; q < 8; ++q) acc[q] += p[si[q]];
  }
  for (; e < e1; ++e) acc[0] += p[(int)pk[e].x];
  s += ((acc[0]+acc[1])+(acc[2]+acc[3])) + ((acc[4]+acc[5])+(acc[6]+acc[7]));
  out[r] = invw[r] * s + wr[r] + b3[0];
}

extern "C" void kernel_launch(void* const* d_in, const int* in_sizes, int n_in,
                              void* d_out, int out_size, void* d_ws, size_t ws_size,
                              hipStream_t stream){
  const float* x      = (const float*)d_in[0];
  const void*  ei     = d_in[1];
  const float* ew     = (const float*)d_in[2];
  const float* W1     = (const float*)d_in[3];
  const float* b1     = (const float*)d_in[4];
  const float* Wc     = (const float*)d_in[5];
  const float* bc     = (const float*)d_in[6];
  const float* W_out  = (const float*)d_in[7];
  const float* W_root = (const float*)d_in[8];
  const float* b3     = (const float*)d_in[9];
  const int N = in_sizes[0] / 512;
  const int E = in_sizes[2];

  char* w = (char*)d_ws;
  auto alloc = [&](size_t bytes)->void*{ void* r = (void*)w; w += (bytes + 255) & ~(size_t)255; return r; };
  unsigned short* h1b = (unsigned short*)alloc((size_t)N * 256 * 2 * 2);
  float* B0 = (float*)h1b;
  float* B1 = B0 + (size_t)N * 128;
  float* B2 = (float*)alloc((size_t)N * 128 * 4);
  unsigned short* C5c = (unsigned short*)B2;
  unsigned short* CC  = (unsigned short*)alloc((size_t)N * 768 * 2);
  unsigned short* h0b = (unsigned short*)alloc((size_t)N * 256 * 2);
  unsigned short* Bb0 = h0b;
  unsigned short* Bb1 = h0b + (size_t)N * 128;
  uint2* csr_sw  = (uint2*)alloc((size_t)E * 8);
  uint2* pk_gcn  = (uint2*)alloc((size_t)E * 8);
  uint2* pk_cheb = (uint2*)alloc((size_t)E * 8);
  uint2* part    = (uint2*)alloc((size_t)E * 8);
  int nblk = ceil_div(E, EPB);
  int*   block_hist  = (int*)alloc((size_t)nblk * 512 * 4);
  int*   off_hist    = (int*)alloc((size_t)nblk * 512 * 4);
  int*   bucket_total= (int*)alloc(512 * 4);
  int*   bucket_base = (int*)alloc(513 * 4);
  int*   row_ptr = (int*)  alloc((size_t)(N + 1) * 4);
  float* dis1    = (float*)alloc((size_t)N * 4);
  float* dis2    = (float*)alloc((size_t)N * 4);
  float* invw    = (float*)alloc((size_t)N * 4);
  float* pbuf    = (float*)alloc((size_t)N * 4);
  float* wrbuf   = (float*)alloc((size_t)N * 4);
  short* W1t_h   = (short*)alloc((size_t)512 * 256 * 2);
  short* Wct_h   = (short*)alloc((size_t)768 * 256 * 2);
  int*   flag    = (int*)  alloc(256);

  hipMemsetAsync(flag, 0, 4, stream);

  k_detect<<<16, 256, 0, stream>>>((const int*)ei, E, flag);
  k_hist<<<nblk, 256, 0, stream>>>(ei, E, flag, block_hist);
  k_colscan<<<512, 64, 0, stream>>>(block_hist, off_hist, bucket_total, nblk);
  k_bucketbase<<<1, 512, 0, stream>>>(bucket_total, bucket_base, row_ptr, N, E);
  k_partition<<<nblk, 256, 0, stream>>>(ei, ew, E, flag, off_hist, bucket_base, part);
  int nbkt = ceil_div(N, 256);
  k_bucket_csr<<<nbkt, 256, 0, stream>>>(part, bucket_base, csr_sw, row_ptr, dis1, dis2, invw, N);
  k_norm<<<ceil_div(E, 256), 256, 0, stream>>>(csr_sw, dis1, dis2, pk_gcn, pk_cheb, E);

  k_prep_w1<<<ceil_div(512 * 256, 256), 256, 0, stream>>>(W1, W1t_h);
  k_prep_wc<<<ceil_div(768 * 256, 256), 256, 0, stream>>>(Wc, Wct_h);

  // ---- GCNConv: h0b = bf16(x@W1); h1b = bf16(relu(agg + b1)) ----
  int nbm = ceil_div(N, 128);
  int grid1 = 8 * 2 * ceil_div(nbm, 8);
  k_gemm_mfma<<<grid1, 256, 0, stream>>>(x, W1t_h, h0b, N, 256, 512, nbm);
  k_gcn_agg<<<ceil_div(N, 4), 256, 0, stream>>>(h0b, pk_gcn, row_ptr, dis1, b1, h1b, N);

  // ---- fused Cheb projection ----
  int grid2 = 8 * 6 * ceil_div(nbm, 8);
  k_gemm_mfma2<<<grid2, 256, 0, stream>>>(h1b, Wct_h, CC, C5c, N, 768, 256, nbm);

  // ---- Clenshaw ----
  auto spmm = [&](const unsigned short* Ck, const unsigned short* s16, int s16s, const float* sf,
                  const unsigned short* src, int ss, float* dst, unsigned short* dstb, float coef){
    k_cheb_spmm2<<<ceil_div(N, 4), 256, 0, stream>>>(Ck, 768, s16, s16s, sf, src, ss, dst, dstb,
        pk_cheb, row_ptr, dis2, coef, N);
  };
  // b4 = C4 + 2L b5
  spmm(CC + 4*128, nullptr, 0, nullptr, C5c, 128, B0, Bb0, -2.f);
  // b3 = C3 - b5 + 2L b4
  spmm(CC + 3*128, C5c, 128, nullptr, Bb0, 128, B1, Bb1, -2.f);
  // b2 = C2 - b4 + 2L b3
  spmm(CC + 2*128, nullptr, 0, B0, Bb1, 128, B2, Bb0, -2.f);
  // b1 = C1 - b3 + 2L b2  (fp32 dst never read -> bf16 only)
  spmm(CC + 1*128, nullptr, 0, B1, Bb0, 128, nullptr, Bb1, -2.f);

  // ---- final: res = C0 - b2 + L b1, fused with feat/p/wr epilogue ----
  float* out  = (float*)d_out;
  float* feat = out + N;
  k_spmm_final<<<ceil_div(N, 4), 256, 0, stream>>>(CC + 0*128, 768, B2, Bb1, 128,
      bc, W_out, W_root, feat, pbuf, wrbuf, pk_cheb, row_ptr, dis2, -1.f, N);
  k_out<<<ceil_div(N, 256), 256, 0, stream>>>(pbuf, wrbuf, invw, pk_cheb, row_ptr, b3, out, N);
}